// Round 5
// baseline (160.178 us; speedup 1.0000x reference)
//
#include <hip/hip_runtime.h>

#define NN 50000
#define NE 800000
#define FIN 128
#define NH 4
#define OPH 32
#define FOUT 128
#define NSLOPE 0.2f
#define NWHB ((NN + 31) / 32)      // 1563 projection blocks
#define NSCB ((NE + 255) / 256)    // 3125 scatter blocks

// round-to-nearest-even f32 -> bf16 (finite values)
static __device__ __forceinline__ unsigned int f2bf(float f) {
  unsigned int u = __float_as_uint(f);
  u += 0x7fffu + ((u >> 16) & 1u);
  return u >> 16;
}

// ---------------------------------------------------------------------------
// Histogram of dst (must precede the scan).
// ---------------------------------------------------------------------------
__global__ void k_hist(const int* __restrict__ dst, int* __restrict__ counts) {
  const int i = blockIdx.x * blockDim.x + threadIdx.x;
  if (i < NE) atomicAdd(&counts[dst[i]], 1);
}

// ---------------------------------------------------------------------------
// Exclusive scan over counts (3 small kernels). scan3 also seeds cursor.
// ---------------------------------------------------------------------------
__global__ __launch_bounds__(512) void k_scan1(const int* __restrict__ counts,
                                               int* __restrict__ offsets,
                                               int* __restrict__ bsums) {
  __shared__ int buf[512];
  const int gid = blockIdx.x * 512 + threadIdx.x;
  const int v = (gid < NN) ? counts[gid] : 0;
  buf[threadIdx.x] = v;
  __syncthreads();
  int incl = v;
  for (int d = 1; d < 512; d <<= 1) {
    const int add = (threadIdx.x >= d) ? buf[threadIdx.x - d] : 0;
    __syncthreads();
    incl += add;
    buf[threadIdx.x] = incl;
    __syncthreads();
  }
  if (gid < NN) offsets[gid] = incl - v;
  if (threadIdx.x == 511) bsums[blockIdx.x] = incl;
}

__global__ __launch_bounds__(128) void k_scan2(int* __restrict__ bsums, int nb) {
  __shared__ int buf[128];
  const int v = (threadIdx.x < nb) ? bsums[threadIdx.x] : 0;
  buf[threadIdx.x] = v;
  __syncthreads();
  int incl = v;
  for (int d = 1; d < 128; d <<= 1) {
    const int add = (threadIdx.x >= d) ? buf[threadIdx.x - d] : 0;
    __syncthreads();
    incl += add;
    buf[threadIdx.x] = incl;
    __syncthreads();
  }
  if (threadIdx.x < nb) bsums[threadIdx.x] = incl - v;
}

__global__ __launch_bounds__(512) void k_scan3(int* __restrict__ offsets,
                                               const int* __restrict__ bsums,
                                               int* __restrict__ cursor) {
  const int gid = blockIdx.x * 512 + threadIdx.x;
  if (gid < NN) {
    const int v = offsets[gid] + bsums[blockIdx.x];
    offsets[gid] = v;
    cursor[gid] = v;            // scatter then needs ONE atomic, no offsets read
  }
  if (gid == NN) offsets[NN] = NE;
}

// ---------------------------------------------------------------------------
// Fused kernel: interleaved block roles so scatter (L2-latency-bound) and the
// projection (VALU/LDS-bound) co-reside on every CU.
//   bid % 3 == 0          -> projection block (1563 total)
//   bid % 3 == 1 or 2     -> scatter block    (3125 total)
// Projection: Whh[n][c] (bf16) = sum_f x[n][f]*W[h][f][o]; e_l4/e_r4 dots.
// Scatter:    pos = cursor[d]++; srcs[pos] = src[i].
// ---------------------------------------------------------------------------
__global__ __launch_bounds__(256) void k_scat_wh(
    const float* __restrict__ x, const float* __restrict__ W,
    const float* __restrict__ a_l, const float* __restrict__ a_r,
    const int* __restrict__ src, const int* __restrict__ dst,
    int* __restrict__ cursor, int* __restrict__ srcs,
    unsigned int* __restrict__ Whh, float* __restrict__ e_l4,
    float* __restrict__ e_r4) {
  __shared__ float xs[32 * 128];   // 16 KB
  const int t = threadIdx.x;
  const int bid = blockIdx.x;
  const int r = bid % 3;

  if (r != 0) {                    // ---- scatter role ----
    const int sb = (bid / 3) * 2 + (r - 1);
    const int i = sb * 256 + t;
    if (i < NE) {
      const int d = dst[i];
      const int pos = atomicAdd(&cursor[d], 1);
      srcs[pos] = src[i];
    }
    return;
  }

  // ---- projection role ----
  const int n0 = (bid / 3) * 32;

  // stage x[n0..n0+31][:] -> LDS (1024 float4, coalesced)
#pragma unroll
  for (int i = 0; i < 4; ++i) {
    const int li = t + i * 256;
    const long gf = (long)n0 * FIN + li * 4;
    float4 v;
    if (gf + 3 < (long)NN * FIN) v = *(const float4*)(x + gf);
    else v = make_float4(0.f, 0.f, 0.f, 0.f);
    *(float4*)&xs[li * 4] = v;
  }
  __syncthreads();

  const int tx = t & 31;            // col group: c0 = tx*4
  const int ty = t >> 5;            // node group: n0 + ty*4 + (0..3)
  const int c0 = tx * 4;
  const int h = tx >> 3;
  const int o0 = (tx & 7) * 4;

  float acc[4][4];
#pragma unroll
  for (int a = 0; a < 4; ++a)
#pragma unroll
    for (int b = 0; b < 4; ++b) acc[a][b] = 0.f;

  const float* __restrict__ Wp = W + h * (FIN * OPH) + o0;

  for (int f0 = 0; f0 < FIN; f0 += 4) {
    float4 wv[4];
#pragma unroll
    for (int ff = 0; ff < 4; ++ff)
      wv[ff] = *(const float4*)(Wp + (f0 + ff) * OPH);
    float4 xv[4];
#pragma unroll
    for (int nl = 0; nl < 4; ++nl)
      xv[nl] = *(const float4*)&xs[(ty * 4 + nl) * FIN + f0];
#pragma unroll
    for (int nl = 0; nl < 4; ++nl) {
      acc[nl][0] = fmaf(xv[nl].x, wv[0].x, acc[nl][0]);
      acc[nl][1] = fmaf(xv[nl].x, wv[0].y, acc[nl][1]);
      acc[nl][2] = fmaf(xv[nl].x, wv[0].z, acc[nl][2]);
      acc[nl][3] = fmaf(xv[nl].x, wv[0].w, acc[nl][3]);
      acc[nl][0] = fmaf(xv[nl].y, wv[1].x, acc[nl][0]);
      acc[nl][1] = fmaf(xv[nl].y, wv[1].y, acc[nl][1]);
      acc[nl][2] = fmaf(xv[nl].y, wv[1].z, acc[nl][2]);
      acc[nl][3] = fmaf(xv[nl].y, wv[1].w, acc[nl][3]);
      acc[nl][0] = fmaf(xv[nl].z, wv[2].x, acc[nl][0]);
      acc[nl][1] = fmaf(xv[nl].z, wv[2].y, acc[nl][1]);
      acc[nl][2] = fmaf(xv[nl].z, wv[2].z, acc[nl][2]);
      acc[nl][3] = fmaf(xv[nl].z, wv[2].w, acc[nl][3]);
      acc[nl][0] = fmaf(xv[nl].w, wv[3].x, acc[nl][0]);
      acc[nl][1] = fmaf(xv[nl].w, wv[3].y, acc[nl][1]);
      acc[nl][2] = fmaf(xv[nl].w, wv[3].z, acc[nl][2]);
      acc[nl][3] = fmaf(xv[nl].w, wv[3].w, acc[nl][3]);
    }
  }

  const float4 al4 = *(const float4*)&a_l[c0];
  const float4 ar4 = *(const float4*)&a_r[c0];
#pragma unroll
  for (int nl = 0; nl < 4; ++nl) {
    const int n = n0 + ty * 4 + nl;
    if (n >= NN) continue;
    uint2 pk;
    pk.x = f2bf(acc[nl][0]) | (f2bf(acc[nl][1]) << 16);
    pk.y = f2bf(acc[nl][2]) | (f2bf(acc[nl][3]) << 16);
    *(uint2*)&Whh[(size_t)n * 64 + tx * 2] = pk;   // bf16 row, 8B store
    float pl = acc[nl][0] * al4.x + acc[nl][1] * al4.y +
               acc[nl][2] * al4.z + acc[nl][3] * al4.w;
    float pr = acc[nl][0] * ar4.x + acc[nl][1] * ar4.y +
               acc[nl][2] * ar4.z + acc[nl][3] * ar4.w;
#pragma unroll
    for (int mm = 4; mm >= 1; mm >>= 1) {   // sum the 8 col-groups of head h
      pl += __shfl_xor(pl, mm);
      pr += __shfl_xor(pr, mm);
    }
    if ((tx & 7) == 0) {
      e_l4[n * NH + h] = pl;
      e_r4[n * NH + h] = pr;
    }
  }
}

// ---------------------------------------------------------------------------
// Aggregation: one WAVE per node, zero barriers. Lane owns cols
// {2*lane, 2*lane+1} (same head h = lane>>4 -> one weight, one bf16x2 dword).
// ---------------------------------------------------------------------------
__global__ __launch_bounds__(256) void k_agg(
    const int* __restrict__ srcs, const int* __restrict__ offsets,
    const float* __restrict__ e_l4, const float* __restrict__ e_r4,
    const unsigned int* __restrict__ Whh, float* __restrict__ out) {
  __shared__ int ssh[4][64];
  __shared__ float exh[4][64][4];

  const int w = threadIdx.x >> 6;
  const int lane = threadIdx.x & 63;
  const int n = blockIdx.x * 4 + w;

  const int beg = offsets[n];
  const int end = offsets[n + 1];
  const int deg = end - beg;
  const float4 ern = *(const float4*)&e_r4[n * NH];
  const int h = lane >> 4;

  float m0 = -1e9f, m1 = -1e9f, m2 = -1e9f, m3 = -1e9f;
  float D0 = 0.f, D1 = 0.f, D2 = 0.f, D3 = 0.f;
  float acc0 = 0.f, acc1 = 0.f;

  if (deg <= 64) {
    // ---- fast path: one pass, logits in registers ----
    int s = 0;
    float l0 = -1e9f, l1 = -1e9f, l2 = -1e9f, l3 = -1e9f;
    if (lane < deg) {
      s = srcs[beg + lane];
      const float4 el = *(const float4*)&e_l4[s * NH];   // L2-resident table
      l0 = el.x + ern.x; l0 = (l0 >= 0.f) ? l0 : NSLOPE * l0;
      l1 = el.y + ern.y; l1 = (l1 >= 0.f) ? l1 : NSLOPE * l1;
      l2 = el.z + ern.z; l2 = (l2 >= 0.f) ? l2 : NSLOPE * l2;
      l3 = el.w + ern.w; l3 = (l3 >= 0.f) ? l3 : NSLOPE * l3;
    }
    m0 = l0; m1 = l1; m2 = l2; m3 = l3;
#pragma unroll
    for (int mm = 32; mm >= 1; mm >>= 1) {
      m0 = fmaxf(m0, __shfl_xor(m0, mm));
      m1 = fmaxf(m1, __shfl_xor(m1, mm));
      m2 = fmaxf(m2, __shfl_xor(m2, mm));
      m3 = fmaxf(m3, __shfl_xor(m3, mm));
    }
    float e0 = 0.f, e1 = 0.f, e2 = 0.f, e3 = 0.f;
    if (lane < deg) {
      e0 = __expf(l0 - m0); e1 = __expf(l1 - m1);
      e2 = __expf(l2 - m2); e3 = __expf(l3 - m3);
      ssh[w][lane] = s;
      *(float4*)exh[w][lane] = make_float4(e0, e1, e2, e3);
    }
    D0 = e0; D1 = e1; D2 = e2; D3 = e3;
#pragma unroll 4
    for (int jl = 0; jl < deg; ++jl) {
      const int sj = ssh[w][jl];
      const float wH = exh[w][jl][h];
      const unsigned int v = Whh[(size_t)sj * 64 + lane];
      acc0 = fmaf(wH, __uint_as_float(v << 16), acc0);
      acc1 = fmaf(wH, __uint_as_float(v & 0xffff0000u), acc1);
    }
  } else {
    // ---- general path (deg>64 rare at E/N=16): max pass, then chunks ----
    for (int j = beg + lane; j < end; j += 64) {
      const int s = srcs[j];
      const float4 el = *(const float4*)&e_l4[s * NH];
      float l0 = el.x + ern.x; l0 = (l0 >= 0.f) ? l0 : NSLOPE * l0;
      float l1 = el.y + ern.y; l1 = (l1 >= 0.f) ? l1 : NSLOPE * l1;
      float l2 = el.z + ern.z; l2 = (l2 >= 0.f) ? l2 : NSLOPE * l2;
      float l3 = el.w + ern.w; l3 = (l3 >= 0.f) ? l3 : NSLOPE * l3;
      m0 = fmaxf(m0, l0); m1 = fmaxf(m1, l1);
      m2 = fmaxf(m2, l2); m3 = fmaxf(m3, l3);
    }
#pragma unroll
    for (int mm = 32; mm >= 1; mm >>= 1) {
      m0 = fmaxf(m0, __shfl_xor(m0, mm));
      m1 = fmaxf(m1, __shfl_xor(m1, mm));
      m2 = fmaxf(m2, __shfl_xor(m2, mm));
      m3 = fmaxf(m3, __shfl_xor(m3, mm));
    }
    for (int c0 = beg; c0 < end; c0 += 64) {
      const int cnt = min(64, end - c0);
      if (lane < cnt) {
        const int j = c0 + lane;
        const int s = srcs[j];
        const float4 el = *(const float4*)&e_l4[s * NH];
        float l0 = el.x + ern.x; l0 = (l0 >= 0.f) ? l0 : NSLOPE * l0;
        float l1 = el.y + ern.y; l1 = (l1 >= 0.f) ? l1 : NSLOPE * l1;
        float l2 = el.z + ern.z; l2 = (l2 >= 0.f) ? l2 : NSLOPE * l2;
        float l3 = el.w + ern.w; l3 = (l3 >= 0.f) ? l3 : NSLOPE * l3;
        const float e0 = __expf(l0 - m0);
        const float e1 = __expf(l1 - m1);
        const float e2 = __expf(l2 - m2);
        const float e3 = __expf(l3 - m3);
        D0 += e0; D1 += e1; D2 += e2; D3 += e3;
        ssh[w][lane] = s;
        *(float4*)exh[w][lane] = make_float4(e0, e1, e2, e3);
      }
#pragma unroll 4
      for (int jl = 0; jl < cnt; ++jl) {
        const int sj = ssh[w][jl];
        const float wH = exh[w][jl][h];
        const unsigned int v = Whh[(size_t)sj * 64 + lane];
        acc0 = fmaf(wH, __uint_as_float(v << 16), acc0);
        acc1 = fmaf(wH, __uint_as_float(v & 0xffff0000u), acc1);
      }
    }
  }

#pragma unroll
  for (int mm = 32; mm >= 1; mm >>= 1) {
    D0 += __shfl_xor(D0, mm);
    D1 += __shfl_xor(D1, mm);
    D2 += __shfl_xor(D2, mm);
    D3 += __shfl_xor(D3, mm);
  }
  const float dH = (h == 0) ? D0 : (h == 1) ? D1 : (h == 2) ? D2 : D3;
  const float inv = 1.f / (dH + 1e-16f);
  *(float2*)&out[(size_t)n * FOUT + 2 * lane] =
      make_float2(acc0 * inv, acc1 * inv);
}

// ---------------------------------------------------------------------------
extern "C" void kernel_launch(void* const* d_in, const int* in_sizes, int n_in,
                              void* d_out, int out_size, void* d_ws, size_t ws_size,
                              hipStream_t stream) {
  const float* x   = (const float*)d_in[0];
  const int*   ei  = (const int*)d_in[1];   // [2][E]: src = ei, dst = ei + NE
  const float* W   = (const float*)d_in[2];
  const float* a_l = (const float*)d_in[3];
  const float* a_r = (const float*)d_in[4];
  float* out = (float*)d_out;

  const int* src = ei;
  const int* dst = ei + NE;

  // workspace layout (4-byte elements, 16B-aligned arrays first)
  unsigned int* Whh = (unsigned int*)d_ws;           // NN*64 uints (bf16x2)
  float* e_l4    = (float*)(Whh + (size_t)NN * 64);  // NN*4
  float* e_r4    = e_l4 + NN * NH;                   // NN*4
  int*   counts  = (int*)(e_r4 + NN * NH);           // NN
  int*   cursor  = counts + NN;                      // NN
  int*   offsets = cursor + NN;                      // NN+1
  int*   bsums   = offsets + NN + 1;                 // 128
  int*   srcs    = bsums + 128;                      // NE
  (void)ws_size; (void)in_sizes; (void)n_in; (void)out_size;

  hipMemsetAsync(counts, 0, sizeof(int) * NN, stream);

  k_hist<<<NSCB, 256, 0, stream>>>(dst, counts);

  const int nblk = (NN + 511) / 512;  // 98
  k_scan1<<<nblk, 512, 0, stream>>>(counts, offsets, bsums);
  k_scan2<<<1, 128, 0, stream>>>(bsums, nblk);
  k_scan3<<<nblk, 512, 0, stream>>>(offsets, bsums, cursor);

  k_scat_wh<<<NWHB + NSCB, 256, 0, stream>>>(x, W, a_l, a_r, src, dst,
                                             cursor, srcs, Whh, e_l4, e_r4);

  k_agg<<<NN / 4, 256, 0, stream>>>(srcs, offsets, e_l4, e_r4, Whh, out);
}

// Round 6
// 141.922 us; speedup vs baseline: 1.1286x; 1.1286x over previous
//
#include <hip/hip_runtime.h>

#define NN 50000
#define NE 800000
#define FIN 128
#define NH 4
#define OPH 32
#define FOUT 128
#define NSLOPE 0.2f
#define NWHB ((NN + 31) / 32)      // 1563 projection blocks
#define NHISTB ((NE + 255) / 256)  // 3125 hist blocks
#define NXCD 8
#define RSPAN ((NN + NXCD - 1) / NXCD)   // 6250 dst nodes per XCD role
#define EPB 1024                          // edges per scatter chunk
#define NCH ((NE + EPB - 1) / EPB)        // 782 chunks

// round-to-nearest-even f32 -> bf16 (finite values)
static __device__ __forceinline__ unsigned int f2bf(float f) {
  unsigned int u = __float_as_uint(f);
  u += 0x7fffu + ((u >> 16) & 1u);
  return u >> 16;
}

// ---------------------------------------------------------------------------
// Fused projection + dst-histogram (R4-proven): blocks [0,NWHB) do the
// projection, [NWHB, NWHB+NHISTB) do the histogram; the atomic-latency-bound
// hist waves hide under the projection's FMA streams.
// ---------------------------------------------------------------------------
__global__ __launch_bounds__(256) void k_wh_hist(
    const float* __restrict__ x, const float* __restrict__ W,
    const float* __restrict__ a_l, const float* __restrict__ a_r,
    const int* __restrict__ dst, int* __restrict__ counts,
    unsigned int* __restrict__ Whh, float* __restrict__ e_l4,
    float* __restrict__ e_r4) {
  __shared__ float xs[32 * 128];   // 16 KB
  const int t = threadIdx.x;

  if (blockIdx.x >= NWHB) {        // ---- histogram part ----
    const int i = (blockIdx.x - NWHB) * 256 + t;
    if (i < NE) atomicAdd(&counts[dst[i]], 1);
    return;
  }

  const int n0 = blockIdx.x * 32;

  // stage x[n0..n0+31][:] -> LDS (1024 float4, coalesced)
#pragma unroll
  for (int i = 0; i < 4; ++i) {
    const int li = t + i * 256;
    const long gf = (long)n0 * FIN + li * 4;
    float4 v;
    if (gf + 3 < (long)NN * FIN) v = *(const float4*)(x + gf);
    else v = make_float4(0.f, 0.f, 0.f, 0.f);
    *(float4*)&xs[li * 4] = v;
  }
  __syncthreads();

  const int tx = t & 31;            // col group: c0 = tx*4
  const int ty = t >> 5;            // node group: n0 + ty*4 + (0..3)
  const int c0 = tx * 4;
  const int h = tx >> 3;
  const int o0 = (tx & 7) * 4;

  float acc[4][4];
#pragma unroll
  for (int a = 0; a < 4; ++a)
#pragma unroll
    for (int b = 0; b < 4; ++b) acc[a][b] = 0.f;

  const float* __restrict__ Wp = W + h * (FIN * OPH) + o0;

  for (int f0 = 0; f0 < FIN; f0 += 4) {
    float4 wv[4];
#pragma unroll
    for (int ff = 0; ff < 4; ++ff)
      wv[ff] = *(const float4*)(Wp + (f0 + ff) * OPH);
    float4 xv[4];
#pragma unroll
    for (int nl = 0; nl < 4; ++nl)
      xv[nl] = *(const float4*)&xs[(ty * 4 + nl) * FIN + f0];
#pragma unroll
    for (int nl = 0; nl < 4; ++nl) {
      acc[nl][0] = fmaf(xv[nl].x, wv[0].x, acc[nl][0]);
      acc[nl][1] = fmaf(xv[nl].x, wv[0].y, acc[nl][1]);
      acc[nl][2] = fmaf(xv[nl].x, wv[0].z, acc[nl][2]);
      acc[nl][3] = fmaf(xv[nl].x, wv[0].w, acc[nl][3]);
      acc[nl][0] = fmaf(xv[nl].y, wv[1].x, acc[nl][0]);
      acc[nl][1] = fmaf(xv[nl].y, wv[1].y, acc[nl][1]);
      acc[nl][2] = fmaf(xv[nl].y, wv[1].z, acc[nl][2]);
      acc[nl][3] = fmaf(xv[nl].y, wv[1].w, acc[nl][3]);
      acc[nl][0] = fmaf(xv[nl].z, wv[2].x, acc[nl][0]);
      acc[nl][1] = fmaf(xv[nl].z, wv[2].y, acc[nl][1]);
      acc[nl][2] = fmaf(xv[nl].z, wv[2].z, acc[nl][2]);
      acc[nl][3] = fmaf(xv[nl].z, wv[2].w, acc[nl][3]);
      acc[nl][0] = fmaf(xv[nl].w, wv[3].x, acc[nl][0]);
      acc[nl][1] = fmaf(xv[nl].w, wv[3].y, acc[nl][1]);
      acc[nl][2] = fmaf(xv[nl].w, wv[3].z, acc[nl][2]);
      acc[nl][3] = fmaf(xv[nl].w, wv[3].w, acc[nl][3]);
    }
  }

  const float4 al4 = *(const float4*)&a_l[c0];
  const float4 ar4 = *(const float4*)&a_r[c0];
#pragma unroll
  for (int nl = 0; nl < 4; ++nl) {
    const int n = n0 + ty * 4 + nl;
    if (n >= NN) continue;
    uint2 pk;
    pk.x = f2bf(acc[nl][0]) | (f2bf(acc[nl][1]) << 16);
    pk.y = f2bf(acc[nl][2]) | (f2bf(acc[nl][3]) << 16);
    *(uint2*)&Whh[(size_t)n * 64 + tx * 2] = pk;   // bf16 row, 8B store
    float pl = acc[nl][0] * al4.x + acc[nl][1] * al4.y +
               acc[nl][2] * al4.z + acc[nl][3] * al4.w;
    float pr = acc[nl][0] * ar4.x + acc[nl][1] * ar4.y +
               acc[nl][2] * ar4.z + acc[nl][3] * ar4.w;
#pragma unroll
    for (int mm = 4; mm >= 1; mm >>= 1) {   // sum the 8 col-groups of head h
      pl += __shfl_xor(pl, mm);
      pr += __shfl_xor(pr, mm);
    }
    if ((tx & 7) == 0) {
      e_l4[n * NH + h] = pl;
      e_r4[n * NH + h] = pr;
    }
  }
}

// ---------------------------------------------------------------------------
// Exclusive scan over counts (3 small kernels). scan3 also seeds cursor.
// ---------------------------------------------------------------------------
__global__ __launch_bounds__(512) void k_scan1(const int* __restrict__ counts,
                                               int* __restrict__ offsets,
                                               int* __restrict__ bsums) {
  __shared__ int buf[512];
  const int gid = blockIdx.x * 512 + threadIdx.x;
  const int v = (gid < NN) ? counts[gid] : 0;
  buf[threadIdx.x] = v;
  __syncthreads();
  int incl = v;
  for (int d = 1; d < 512; d <<= 1) {
    const int add = (threadIdx.x >= d) ? buf[threadIdx.x - d] : 0;
    __syncthreads();
    incl += add;
    buf[threadIdx.x] = incl;
    __syncthreads();
  }
  if (gid < NN) offsets[gid] = incl - v;
  if (threadIdx.x == 511) bsums[blockIdx.x] = incl;
}

__global__ __launch_bounds__(128) void k_scan2(int* __restrict__ bsums, int nb) {
  __shared__ int buf[128];
  const int v = (threadIdx.x < nb) ? bsums[threadIdx.x] : 0;
  buf[threadIdx.x] = v;
  __syncthreads();
  int incl = v;
  for (int d = 1; d < 128; d <<= 1) {
    const int add = (threadIdx.x >= d) ? buf[threadIdx.x - d] : 0;
    __syncthreads();
    incl += add;
    buf[threadIdx.x] = incl;
    __syncthreads();
  }
  if (threadIdx.x < nb) bsums[threadIdx.x] = incl - v;
}

__global__ __launch_bounds__(512) void k_scan3(int* __restrict__ offsets,
                                               const int* __restrict__ bsums,
                                               int* __restrict__ cursor) {
  const int gid = blockIdx.x * 512 + threadIdx.x;
  if (gid < NN) {
    const int v = offsets[gid] + bsums[blockIdx.x];
    offsets[gid] = v;
    cursor[gid] = v;            // scatter then needs ONE atomic, no offsets read
  }
  if (gid == NN) offsets[NN] = NE;
}

// ---------------------------------------------------------------------------
// XCD-range-partitioned ticket scatter. role r = bid&7 (round-robin block->XCD
// dispatch) owns dsts [r*RSPAN, (r+1)*RSPAN): its cursor+srcs region stays in
// ONE XCD's L2, so the 64B srcs lines fill completely before write-back
// (kills the 16x partial-line amplification). Each edge chunk is re-read by
// all 8 roles -- sequential reads, L3-absorbed.
// ---------------------------------------------------------------------------
__global__ __launch_bounds__(256) void k_scatter(
    const int* __restrict__ src, const int* __restrict__ dst,
    int* __restrict__ cursor, int* __restrict__ srcs) {
  const int r = blockIdx.x & (NXCD - 1);
  const int c = blockIdx.x >> 3;
  const int lo = r * RSPAN;
  const int hi = lo + RSPAN;
  const int base = c * EPB + threadIdx.x;
#pragma unroll
  for (int k = 0; k < EPB / 256; ++k) {
    const int i = base + k * 256;
    if (i < NE) {
      const int d = dst[i];
      if (d >= lo && d < hi) {
        const int pos = atomicAdd(&cursor[d], 1);
        srcs[pos] = src[i];
      }
    }
  }
}

// ---------------------------------------------------------------------------
// Aggregation: one WAVE per node, zero barriers. Lane owns cols
// {2*lane, 2*lane+1} (same head h = lane>>4 -> one weight, one bf16x2 dword).
// ---------------------------------------------------------------------------
__global__ __launch_bounds__(256) void k_agg(
    const int* __restrict__ srcs, const int* __restrict__ offsets,
    const float* __restrict__ e_l4, const float* __restrict__ e_r4,
    const unsigned int* __restrict__ Whh, float* __restrict__ out) {
  __shared__ int ssh[4][64];
  __shared__ float exh[4][64][4];

  const int w = threadIdx.x >> 6;
  const int lane = threadIdx.x & 63;
  const int n = blockIdx.x * 4 + w;

  const int beg = offsets[n];
  const int end = offsets[n + 1];
  const int deg = end - beg;
  const float4 ern = *(const float4*)&e_r4[n * NH];
  const int h = lane >> 4;

  float m0 = -1e9f, m1 = -1e9f, m2 = -1e9f, m3 = -1e9f;
  float D0 = 0.f, D1 = 0.f, D2 = 0.f, D3 = 0.f;
  float acc0 = 0.f, acc1 = 0.f;

  if (deg <= 64) {
    // ---- fast path: one pass, logits in registers ----
    int s = 0;
    float l0 = -1e9f, l1 = -1e9f, l2 = -1e9f, l3 = -1e9f;
    if (lane < deg) {
      s = srcs[beg + lane];
      const float4 el = *(const float4*)&e_l4[s * NH];   // L2-resident table
      l0 = el.x + ern.x; l0 = (l0 >= 0.f) ? l0 : NSLOPE * l0;
      l1 = el.y + ern.y; l1 = (l1 >= 0.f) ? l1 : NSLOPE * l1;
      l2 = el.z + ern.z; l2 = (l2 >= 0.f) ? l2 : NSLOPE * l2;
      l3 = el.w + ern.w; l3 = (l3 >= 0.f) ? l3 : NSLOPE * l3;
    }
    m0 = l0; m1 = l1; m2 = l2; m3 = l3;
#pragma unroll
    for (int mm = 32; mm >= 1; mm >>= 1) {
      m0 = fmaxf(m0, __shfl_xor(m0, mm));
      m1 = fmaxf(m1, __shfl_xor(m1, mm));
      m2 = fmaxf(m2, __shfl_xor(m2, mm));
      m3 = fmaxf(m3, __shfl_xor(m3, mm));
    }
    float e0 = 0.f, e1 = 0.f, e2 = 0.f, e3 = 0.f;
    if (lane < deg) {
      e0 = __expf(l0 - m0); e1 = __expf(l1 - m1);
      e2 = __expf(l2 - m2); e3 = __expf(l3 - m3);
      ssh[w][lane] = s;
      *(float4*)exh[w][lane] = make_float4(e0, e1, e2, e3);
    }
    D0 = e0; D1 = e1; D2 = e2; D3 = e3;
#pragma unroll 4
    for (int jl = 0; jl < deg; ++jl) {
      const int sj = ssh[w][jl];
      const float wH = exh[w][jl][h];
      const unsigned int v = Whh[(size_t)sj * 64 + lane];
      acc0 = fmaf(wH, __uint_as_float(v << 16), acc0);
      acc1 = fmaf(wH, __uint_as_float(v & 0xffff0000u), acc1);
    }
  } else {
    // ---- general path (deg>64 rare at E/N=16): max pass, then chunks ----
    for (int j = beg + lane; j < end; j += 64) {
      const int s = srcs[j];
      const float4 el = *(const float4*)&e_l4[s * NH];
      float l0 = el.x + ern.x; l0 = (l0 >= 0.f) ? l0 : NSLOPE * l0;
      float l1 = el.y + ern.y; l1 = (l1 >= 0.f) ? l1 : NSLOPE * l1;
      float l2 = el.z + ern.z; l2 = (l2 >= 0.f) ? l2 : NSLOPE * l2;
      float l3 = el.w + ern.w; l3 = (l3 >= 0.f) ? l3 : NSLOPE * l3;
      m0 = fmaxf(m0, l0); m1 = fmaxf(m1, l1);
      m2 = fmaxf(m2, l2); m3 = fmaxf(m3, l3);
    }
#pragma unroll
    for (int mm = 32; mm >= 1; mm >>= 1) {
      m0 = fmaxf(m0, __shfl_xor(m0, mm));
      m1 = fmaxf(m1, __shfl_xor(m1, mm));
      m2 = fmaxf(m2, __shfl_xor(m2, mm));
      m3 = fmaxf(m3, __shfl_xor(m3, mm));
    }
    for (int c0 = beg; c0 < end; c0 += 64) {
      const int cnt = min(64, end - c0);
      if (lane < cnt) {
        const int j = c0 + lane;
        const int s = srcs[j];
        const float4 el = *(const float4*)&e_l4[s * NH];
        float l0 = el.x + ern.x; l0 = (l0 >= 0.f) ? l0 : NSLOPE * l0;
        float l1 = el.y + ern.y; l1 = (l1 >= 0.f) ? l1 : NSLOPE * l1;
        float l2 = el.z + ern.z; l2 = (l2 >= 0.f) ? l2 : NSLOPE * l2;
        float l3 = el.w + ern.w; l3 = (l3 >= 0.f) ? l3 : NSLOPE * l3;
        const float e0 = __expf(l0 - m0);
        const float e1 = __expf(l1 - m1);
        const float e2 = __expf(l2 - m2);
        const float e3 = __expf(l3 - m3);
        D0 += e0; D1 += e1; D2 += e2; D3 += e3;
        ssh[w][lane] = s;
        *(float4*)exh[w][lane] = make_float4(e0, e1, e2, e3);
      }
#pragma unroll 4
      for (int jl = 0; jl < cnt; ++jl) {
        const int sj = ssh[w][jl];
        const float wH = exh[w][jl][h];
        const unsigned int v = Whh[(size_t)sj * 64 + lane];
        acc0 = fmaf(wH, __uint_as_float(v << 16), acc0);
        acc1 = fmaf(wH, __uint_as_float(v & 0xffff0000u), acc1);
      }
    }
  }

#pragma unroll
  for (int mm = 32; mm >= 1; mm >>= 1) {
    D0 += __shfl_xor(D0, mm);
    D1 += __shfl_xor(D1, mm);
    D2 += __shfl_xor(D2, mm);
    D3 += __shfl_xor(D3, mm);
  }
  const float dH = (h == 0) ? D0 : (h == 1) ? D1 : (h == 2) ? D2 : D3;
  const float inv = 1.f / (dH + 1e-16f);
  *(float2*)&out[(size_t)n * FOUT + 2 * lane] =
      make_float2(acc0 * inv, acc1 * inv);
}

// ---------------------------------------------------------------------------
extern "C" void kernel_launch(void* const* d_in, const int* in_sizes, int n_in,
                              void* d_out, int out_size, void* d_ws, size_t ws_size,
                              hipStream_t stream) {
  const float* x   = (const float*)d_in[0];
  const int*   ei  = (const int*)d_in[1];   // [2][E]: src = ei, dst = ei + NE
  const float* W   = (const float*)d_in[2];
  const float* a_l = (const float*)d_in[3];
  const float* a_r = (const float*)d_in[4];
  float* out = (float*)d_out;

  const int* src = ei;
  const int* dst = ei + NE;

  // workspace layout (4-byte elements, 16B-aligned arrays first)
  unsigned int* Whh = (unsigned int*)d_ws;           // NN*64 uints (bf16x2)
  float* e_l4    = (float*)(Whh + (size_t)NN * 64);  // NN*4
  float* e_r4    = e_l4 + NN * NH;                   // NN*4
  int*   counts  = (int*)(e_r4 + NN * NH);           // NN
  int*   cursor  = counts + NN;                      // NN
  int*   offsets = cursor + NN;                      // NN+1
  int*   bsums   = offsets + NN + 1;                 // 128
  int*   srcs    = bsums + 128;                      // NE
  (void)ws_size; (void)in_sizes; (void)n_in; (void)out_size;

  hipMemsetAsync(counts, 0, sizeof(int) * NN, stream);

  k_wh_hist<<<NWHB + NHISTB, 256, 0, stream>>>(x, W, a_l, a_r, dst, counts,
                                               Whh, e_l4, e_r4);

  const int nblk = (NN + 511) / 512;  // 98
  k_scan1<<<nblk, 512, 0, stream>>>(counts, offsets, bsums);
  k_scan2<<<1, 128, 0, stream>>>(bsums, nblk);
  k_scan3<<<nblk, 512, 0, stream>>>(offsets, bsums, cursor);

  k_scatter<<<NXCD * NCH, 256, 0, stream>>>(src, dst, cursor, srcs);

  k_agg<<<NN / 4, 256, 0, stream>>>(srcs, offsets, e_l4, e_r4, Whh, out);
}